// Round 1
// baseline (807.101 us; speedup 1.0000x reference)
//
#include <hip/hip_runtime.h>
#include <math.h>

#define EPS 1e-7f
#define IN1_ELEMS 26214400   // 256*20*20*256 (bf16 elements per plane)
#define BT_ELEMS  5308416    // 256*20736

typedef float fvec4 __attribute__((ext_vector_type(4)));
typedef short short8 __attribute__((ext_vector_type(8)));
typedef __bf16 bf16x8 __attribute__((ext_vector_type(8)));

__device__ inline unsigned short f2bf(float f){
  unsigned int u = __float_as_uint(f);
  unsigned int r = (u + 0x7fffu + ((u >> 16) & 1u)) >> 16;
  return (unsigned short)r;
}
__device__ inline float bf2f(unsigned short h){
  return __uint_as_float(((unsigned int)h) << 16);
}
__device__ inline void async16(unsigned short* dst, const unsigned short* src){
  __builtin_amdgcn_global_load_lds((const __attribute__((address_space(1))) void*)src,
                                   (__attribute__((address_space(3))) void*)dst, 16, 0, 0);
}
__device__ inline fvec4 mfma_bf16(short8 a, short8 b, fvec4 c){
  return __builtin_amdgcn_mfma_f32_16x16x32_bf16(
      __builtin_bit_cast(bf16x8, a), __builtin_bit_cast(bf16x8, b), c, 0, 0, 0);
}

// ---------------- K0: conv2_w -> BT^T (hi/lo bf16 split) ----------------
__global__ __launch_bounds__(256) void wt_kernel(const float* __restrict__ w2,
    unsigned short* __restrict__ BTh, unsigned short* __restrict__ BTl){
  __shared__ float tile[64][65];
  int t = threadIdx.x;
  int k0 = blockIdx.x * 64, oc0 = blockIdx.y * 64;
  #pragma unroll
  for (int p = 0; p < 16; ++p){
    int f = p*256 + t;
    int kr = f >> 6, cc = f & 63;
    tile[kr][cc] = w2[(size_t)(k0 + kr)*256 + oc0 + cc];
  }
  __syncthreads();
  #pragma unroll
  for (int p = 0; p < 16; ++p){
    int f = p*256 + t;
    int ocr = f >> 6, kc = f & 63;
    float v = tile[kc][ocr];
    unsigned short h = f2bf(v);
    size_t idx = (size_t)(oc0 + ocr)*20736 + k0 + kc;
    BTh[idx] = h;
    BTl[idx] = f2bf(v - bf2f(h));
  }
}

// ---------------- K1: conv1 9x9 s1 + bias + relu -> bf16 hi/lo ----------------
__global__ __launch_bounds__(256) void conv1_kernel(const float* __restrict__ img,
    const float* __restrict__ w1, const float* __restrict__ b1,
    unsigned short* __restrict__ outh, unsigned short* __restrict__ outl){
  __shared__ float sim[252];
  int t = threadIdx.x;
  int oh = blockIdx.x, b = blockIdx.y;
  if (t < 252) sim[t] = img[((size_t)b*28 + oh + t/28)*28 + (t%28)];
  __syncthreads();
  float acc[20];
  #pragma unroll
  for (int i = 0; i < 20; ++i) acc[i] = 0.f;
  #pragma unroll
  for (int kh = 0; kh < 9; ++kh){
    float im[28];
    #pragma unroll
    for (int c = 0; c < 28; ++c) im[c] = sim[kh*28 + c];
    #pragma unroll
    for (int kw = 0; kw < 9; ++kw){
      float wv = w1[(kh*9 + kw)*256 + t];
      #pragma unroll
      for (int ow = 0; ow < 20; ++ow) acc[ow] = fmaf(im[ow + kw], wv, acc[ow]);
    }
  }
  float bv = b1[t];
  size_t base = ((size_t)(b*20 + oh))*20*256 + t;
  #pragma unroll
  for (int ow = 0; ow < 20; ++ow){
    float v = fmaxf(acc[ow] + bv, 0.f);
    unsigned short h = f2bf(v);
    outh[base + ow*256] = h;
    outl[base + ow*256] = f2bf(v - bf2f(h));
  }
}

// ---------------- K2: conv2 as implicit GEMM, split-bf16 3-pass MFMA ----------------
// M=9216 (b,oh,ow) x N=256 (oc), K=20736 = 81*(kh,kw) * 256 ic. split-K=4 via atomics.
__global__ __launch_bounds__(256) void conv2_mfma(const unsigned short* __restrict__ in1h,
    const unsigned short* __restrict__ BTh, float* __restrict__ out){
  __shared__ __align__(16) unsigned short lds[16384]; // Ah|Al|Bh|Bl, 4096 shorts each
  const int t = threadIdx.x;
  const int lane = t & 63, w = t >> 6;
  const int m0 = blockIdx.y * 128, n0 = blockIdx.x * 128;
  const int rowA = t >> 2, seg = t & 3;

  const unsigned short* aS[2];
  const unsigned short* bS[2];
  #pragma unroll
  for (int h = 0; h < 2; ++h){
    int m = m0 + h*64 + rowA;
    int bb = m / 36, s = m - bb*36, oh = s / 6, ow = s - oh*6;
    aS[h] = in1h + ((size_t)((bb*20 + 2*oh)*20 + 2*ow))*256 + seg*8;
    int n = n0 + h*64 + rowA;
    bS[h] = BTh + (size_t)n*20736 + seg*8;
  }
  unsigned short* dstA = &lds[rowA*32 + seg*8];
  unsigned short* dstB = &lds[8192 + rowA*32 + seg*8];

  fvec4 acc[4][4];
  #pragma unroll
  for (int i=0;i<4;++i)
    #pragma unroll
    for (int j=0;j<4;++j) acc[i][j] = (fvec4){0.f,0.f,0.f,0.f};

  const int qm = (w >> 1)*64, qn = (w & 1)*64;
  const int ks0 = blockIdx.z * 162, ks1 = ks0 + 162;

  for (int ks = ks0; ks < ks1; ++ks){
    int kk = ks >> 3;
    int kh = kk / 9, kw = kk - kh*9;
    int aoff = (kh*20 + kw)*256 + (ks & 7)*32;
    int boff = ks*32;
    #pragma unroll
    for (int h = 0; h < 2; ++h){
      async16(dstA + h*2048,        aS[h] + aoff);
      async16(dstA + 4096 + h*2048, aS[h] + IN1_ELEMS + aoff);
      async16(dstB + h*2048,        bS[h] + boff);
      async16(dstB + 4096 + h*2048, bS[h] + BT_ELEMS + boff);
    }
    __syncthreads();
    short8 ah[4], al[4], bh[4], bl[4];
    #pragma unroll
    for (int i=0;i<4;++i){
      int ro = (qm + i*16 + (lane & 15))*32 + (lane >> 4)*8;
      ah[i] = *(const short8*)&lds[ro];
      al[i] = *(const short8*)&lds[4096 + ro];
    }
    #pragma unroll
    for (int j=0;j<4;++j){
      int ro = (qn + j*16 + (lane & 15))*32 + (lane >> 4)*8;
      bh[j] = *(const short8*)&lds[8192 + ro];
      bl[j] = *(const short8*)&lds[12288 + ro];
    }
    #pragma unroll
    for (int i=0;i<4;++i)
      #pragma unroll
      for (int j=0;j<4;++j){
        acc[i][j] = mfma_bf16(ah[i], bh[j], acc[i][j]);
        acc[i][j] = mfma_bf16(ah[i], bl[j], acc[i][j]);
        acc[i][j] = mfma_bf16(al[i], bh[j], acc[i][j]);
      }
    __syncthreads();
  }
  #pragma unroll
  for (int i=0;i<4;++i){
    int gm = m0 + qm + i*16 + ((lane >> 4) << 2);
    #pragma unroll
    for (int j=0;j<4;++j){
      int gn = n0 + qn + j*16 + (lane & 15);
      #pragma unroll
      for (int r=0;r<4;++r)
        atomicAdd(&out[(size_t)(gm + r)*256 + gn], acc[i][j][r]);
    }
  }
}

// ---------------- K3: bias + relu + squash -> pc ----------------
__global__ __launch_bounds__(256) void squash_pc_kernel(const float* __restrict__ c2out,
    const float* __restrict__ b2, float* __restrict__ pc){
  int g = blockIdx.x*256 + threadIdx.x;   // 294912 capsules
  const float* s = c2out + (size_t)g*8;
  int oc0 = (g & 31) * 8;
  float v[8], sq = 0.f;
  #pragma unroll
  for (int e=0;e<8;++e){ float x = fmaxf(s[e] + b2[oc0+e], 0.f); v[e] = x; sq += x*x; }
  float fac = sq / ((1.f + sq) * sqrtf(sq + EPS));
  float* o = pc + (size_t)g*8;
  #pragma unroll
  for (int e=0;e<8;++e) o[e] = v[e]*fac;
}

// ---------------- K4a: u_hat (fp32) + s1 partials ----------------
__global__ __launch_bounds__(256) void uhat_producer(const float* __restrict__ pc,
    const float* __restrict__ Wm, float* __restrict__ uhat, float* __restrict__ s1){
  __shared__ float pcl[8192]; // [64 b][16 n][8 i]
  int t = threadIdx.x;
  int n0 = blockIdx.x * 16, b0 = blockIdx.y * 64;
  #pragma unroll
  for (int p = 0; p < 32; ++p){
    int f = p*256 + t;
    int bl = f >> 7, rem = f & 127;
    pcl[f] = pc[((size_t)(b0 + bl)*1152 + n0)*8 + rem];
  }
  __syncthreads();
  for (int r = 0; r < 40; ++r){
    int item = r*256 + t;               // (b_local, cj)
    int bl = item / 160, cj = item - bl*160;
    float s1a = 0.f;
    size_t ub = ((size_t)(b0 + bl)*1152 + n0)*160 + cj;
    const float* pb = &pcl[bl*128];
    #pragma unroll 4
    for (int nl = 0; nl < 16; ++nl){
      const float4* wp = (const float4*)&Wm[((size_t)(n0 + nl)*160 + cj)*8];
      float4 w0 = wp[0], w1 = wp[1];
      const float4* pp = (const float4*)&pb[nl*8];
      float4 p0 = pp[0], p1 = pp[1];
      float uh = w0.x*p0.x + w0.y*p0.y + w0.z*p0.z + w0.w*p0.w
               + w1.x*p1.x + w1.y*p1.y + w1.z*p1.z + w1.w*p1.w;
      uhat[ub + (size_t)nl*160] = uh;
      s1a += uh;
    }
    atomicAdd(&s1[(b0 + bl)*160 + cj], s1a);
  }
}

// ---------------- K4b: v1 = squash(s1/10) ----------------
__global__ __launch_bounds__(64) void squash_v1_kernel(const float* __restrict__ s1,
    float* __restrict__ v1){
  int g = blockIdx.x*64 + threadIdx.x;
  if (g >= 2560) return;
  const float* s = s1 + g*16;
  float x[16], sq = 0.f;
  #pragma unroll
  for (int j=0;j<16;++j){ float v = s[j]*0.1f; x[j] = v; sq += v*v; }
  float fac = sq / ((1.f + sq) * sqrtf(sq + EPS));
  float* o = v1 + g*16;
  #pragma unroll
  for (int j=0;j<16;++j) o[j] = x[j]*fac;
}

// ---------------- K4c: uv -> softmax -> s2 partials ----------------
__global__ __launch_bounds__(256) void routing_kernel(const float* __restrict__ uhat,
    const float* __restrict__ v1, float* __restrict__ s2){
  __shared__ float uvl[1280];   // [128 n][10 c]
  __shared__ float v1l[160];
  int t = threadIdx.x;
  int n0 = blockIdx.x * 128, b = blockIdx.y;
  if (t < 160) v1l[t] = v1[b*160 + t];
  __syncthreads();
  #pragma unroll
  for (int p = 0; p < 5; ++p){
    int item = p*256 + t;
    int nl = item / 10, c = item - nl*10;
    const float4* up = (const float4*)&uhat[((size_t)b*1152 + n0 + nl)*160 + c*16];
    const float* vv = &v1l[c*16];
    float4 q0 = up[0], q1 = up[1], q2 = up[2], q3 = up[3];
    float uv = q0.x*vv[0] + q0.y*vv[1] + q0.z*vv[2] + q0.w*vv[3]
             + q1.x*vv[4] + q1.y*vv[5] + q1.z*vv[6] + q1.w*vv[7]
             + q2.x*vv[8] + q2.y*vv[9] + q2.z*vv[10]+ q2.w*vv[11]
             + q3.x*vv[12]+ q3.y*vv[13]+ q3.z*vv[14]+ q3.w*vv[15];
    uvl[item] = uv;
  }
  __syncthreads();
  if (t < 128){
    float* row = &uvl[t*10];
    float mx = row[0];
    #pragma unroll
    for (int c=1;c<10;++c) mx = fmaxf(mx, row[c]);
    float e[10], sum = 0.f;
    #pragma unroll
    for (int c=0;c<10;++c){ e[c] = expf(row[c]-mx); sum += e[c]; }
    float inv = 1.f/sum;
    #pragma unroll
    for (int c=0;c<10;++c) row[c] = e[c]*inv;
  }
  __syncthreads();
  if (t < 160){
    int c = t >> 4;
    float a = 0.f;
    const float* ub = &uhat[((size_t)b*1152 + n0)*160 + t];
    for (int nl = 0; nl < 128; ++nl)
      a = fmaf(uvl[nl*10 + c], ub[(size_t)nl*160], a);
    atomicAdd(&s2[b*160 + t], a);
  }
}

// ---------------- K4d: v2, norms, argmax, mask ----------------
__global__ __launch_bounds__(64) void finalize_kernel(const float* __restrict__ s2,
    const int* __restrict__ target, float* __restrict__ out_norm,
    float* __restrict__ out_pred, float* __restrict__ masked){
  __shared__ float v2l[160];
  __shared__ float nrm[10];
  int b = blockIdx.x, t = threadIdx.x;
  if (t < 10){
    const float* s = s2 + b*160 + t*16;
    float x[16], sq = 0.f;
    #pragma unroll
    for (int j=0;j<16;++j){ x[j] = s[j]; sq += x[j]*x[j]; }
    float fac = sq / ((1.f + sq) * sqrtf(sq + EPS));
    float n2 = 0.f;
    #pragma unroll
    for (int j=0;j<16;++j){ float v = x[j]*fac; v2l[t*16+j] = v; n2 += v*v; }
    float nr = sqrtf(n2 + EPS);
    nrm[t] = nr;
    out_norm[b*10 + t] = nr;
  }
  __syncthreads();
  if (t == 0){
    int am = 0; float bv = nrm[0];
    #pragma unroll
    for (int c=1;c<10;++c) if (nrm[c] > bv){ bv = nrm[c]; am = c; }
    out_pred[b] = (float)am;
  }
  int tg = target[b];
  #pragma unroll
  for (int p = 0; p < 3; ++p){
    int cj = p*64 + t;
    if (cj < 160) masked[b*160 + cj] = ((cj >> 4) == tg) ? v2l[cj] : 0.f;
  }
}

// ---------------- decoder GEMMs (M=256 fixed) ----------------
__global__ __launch_bounds__(256) void dec_gemm(const float* __restrict__ A,
    const float* __restrict__ B, const float* __restrict__ bias, float* __restrict__ C,
    int K, int N, int act){
  int t = threadIdx.x;
  int n = blockIdx.x*64 + (t & 63);
  int m = blockIdx.y*4 + (t >> 6);
  if (n >= N) return;
  float acc = 0.f;
  const float* a = A + (size_t)m*K;
  const float* bp = B + n;
  #pragma unroll 8
  for (int k = 0; k < K; ++k) acc = fmaf(a[k], bp[(size_t)k*N], acc);
  acc += bias[n];
  if (act == 0) acc = fmaxf(acc, 0.f);
  else acc = 1.f/(1.f + expf(-acc));
  C[(size_t)m*N + n] = acc;
}

extern "C" void kernel_launch(void* const* d_in, const int* in_sizes, int n_in,
                              void* d_out, int out_size, void* d_ws, size_t ws_size,
                              hipStream_t stream) {
  const float* image   = (const float*)d_in[0];
  const int*   target  = (const int*)d_in[1];
  const float* conv1_w = (const float*)d_in[2];
  const float* conv1_b = (const float*)d_in[3];
  const float* conv2_w = (const float*)d_in[4];
  const float* conv2_b = (const float*)d_in[5];
  const float* Wm      = (const float*)d_in[6];
  const float* d1_w    = (const float*)d_in[7];
  const float* d1_b    = (const float*)d_in[8];
  const float* d2_w    = (const float*)d_in[9];
  const float* d2_b    = (const float*)d_in[10];
  const float* d3_w    = (const float*)d_in[11];
  const float* d3_b    = (const float*)d_in[12];

  char* ws = (char*)d_ws;
  // region plan (u_hat overlays conv-phase buffers, which are dead by then):
  unsigned short* in1h = (unsigned short*)(ws);               // +52428800: in1l
  unsigned short* BTh  = (unsigned short*)(ws + 104857600);   // +10616832: BTl
  float* uhat   = (float*)(ws);                               // [0, 188743680)
  float* c2out  = (float*)(ws + 126091264);                   // 9437184 B
  float* pc     = (float*)(ws + 188743680);                   // 9437184 B
  float* s1     = (float*)(ws + 198180864);                   // 163840 B
  float* s2     = (float*)(ws + 198344704);                   // 163840 B
  float* v1     = (float*)(ws + 198508544);                   // 163840 B
  float* masked = (float*)(ws + 198672384);                   // 163840 B
  float* h1     = (float*)(ws + 198836224);                   // 524288 B
  float* h2     = (float*)(ws + 199360512);                   // 1048576 B

  float* out_norm = (float*)d_out;            // 2560
  float* out_pred = out_norm + 2560;          // 256
  float* dec      = out_norm + 2816;          // 200704

  wt_kernel<<<dim3(324,4),256,0,stream>>>(conv2_w, BTh, BTh + BT_ELEMS);
  conv1_kernel<<<dim3(20,256),256,0,stream>>>(image, conv1_w, conv1_b, in1h, in1h + IN1_ELEMS);
  hipMemsetAsync(c2out, 0, 9437184, stream);
  conv2_mfma<<<dim3(2,72,4),256,0,stream>>>(in1h, BTh, c2out);
  squash_pc_kernel<<<dim3(1152),256,0,stream>>>(c2out, conv2_b, pc);
  hipMemsetAsync(s1, 0, 327680, stream);  // zero s1 + s2 (contiguous)
  uhat_producer<<<dim3(72,4),256,0,stream>>>(pc, Wm, uhat, s1);
  squash_v1_kernel<<<dim3(40),64,0,stream>>>(s1, v1);
  routing_kernel<<<dim3(9,256),256,0,stream>>>(uhat, v1, s2);
  finalize_kernel<<<dim3(256),64,0,stream>>>(s2, target, out_norm, out_pred, masked);
  dec_gemm<<<dim3(8,64),256,0,stream>>>(masked, d1_w, d1_b, h1, 160, 512, 0);
  dec_gemm<<<dim3(16,64),256,0,stream>>>(h1, d2_w, d2_b, h2, 512, 1024, 0);
  dec_gemm<<<dim3(13,64),256,0,stream>>>(h2, d3_w, d3_b, dec, 1024, 784, 1);
}

// Round 2
// 764.123 us; speedup vs baseline: 1.0562x; 1.0562x over previous
//
#include <hip/hip_runtime.h>
#include <math.h>

#define EPS 1e-7f
#define IN1_ELEMS 26214400   // 256*20*20*256 (bf16 elements per plane)
#define BT_ELEMS  5308416    // 256*20736

typedef float fvec4 __attribute__((ext_vector_type(4)));
typedef short short8 __attribute__((ext_vector_type(8)));
typedef __bf16 bf16x8 __attribute__((ext_vector_type(8)));

__device__ inline unsigned short f2bf(float f){
  unsigned int u = __float_as_uint(f);
  unsigned int r = (u + 0x7fffu + ((u >> 16) & 1u)) >> 16;
  return (unsigned short)r;
}
__device__ inline float bf2f(unsigned short h){
  return __uint_as_float(((unsigned int)h) << 16);
}
__device__ inline void async16(unsigned short* dst, const unsigned short* src){
  __builtin_amdgcn_global_load_lds((const __attribute__((address_space(1))) void*)src,
                                   (__attribute__((address_space(3))) void*)dst, 16, 0, 0);
}
__device__ inline fvec4 mfma_bf16(short8 a, short8 b, fvec4 c){
  return __builtin_amdgcn_mfma_f32_16x16x32_bf16(
      __builtin_bit_cast(bf16x8, a), __builtin_bit_cast(bf16x8, b), c, 0, 0, 0);
}

// ---------------- K0: conv2_w -> BT^T (hi/lo bf16 split) ----------------
__global__ __launch_bounds__(256) void wt_kernel(const float* __restrict__ w2,
    unsigned short* __restrict__ BTh, unsigned short* __restrict__ BTl){
  __shared__ float tile[64][65];
  int t = threadIdx.x;
  int k0 = blockIdx.x * 64, oc0 = blockIdx.y * 64;
  #pragma unroll
  for (int p = 0; p < 16; ++p){
    int f = p*256 + t;
    int kr = f >> 6, cc = f & 63;
    tile[kr][cc] = w2[(size_t)(k0 + kr)*256 + oc0 + cc];
  }
  __syncthreads();
  #pragma unroll
  for (int p = 0; p < 16; ++p){
    int f = p*256 + t;
    int ocr = f >> 6, kc = f & 63;
    float v = tile[kc][ocr];
    unsigned short h = f2bf(v);
    size_t idx = (size_t)(oc0 + ocr)*20736 + k0 + kc;
    BTh[idx] = h;
    BTl[idx] = f2bf(v - bf2f(h));
  }
}

// ---------------- K1: conv1 9x9 s1 + bias + relu -> bf16 hi/lo ----------------
__global__ __launch_bounds__(256) void conv1_kernel(const float* __restrict__ img,
    const float* __restrict__ w1, const float* __restrict__ b1,
    unsigned short* __restrict__ outh, unsigned short* __restrict__ outl){
  __shared__ float sim[252];
  int t = threadIdx.x;
  int oh = blockIdx.x, b = blockIdx.y;
  if (t < 252) sim[t] = img[((size_t)b*28 + oh + t/28)*28 + (t%28)];
  __syncthreads();
  float acc[20];
  #pragma unroll
  for (int i = 0; i < 20; ++i) acc[i] = 0.f;
  #pragma unroll
  for (int kh = 0; kh < 9; ++kh){
    float im[28];
    #pragma unroll
    for (int c = 0; c < 28; ++c) im[c] = sim[kh*28 + c];
    #pragma unroll
    for (int kw = 0; kw < 9; ++kw){
      float wv = w1[(kh*9 + kw)*256 + t];
      #pragma unroll
      for (int ow = 0; ow < 20; ++ow) acc[ow] = fmaf(im[ow + kw], wv, acc[ow]);
    }
  }
  float bv = b1[t];
  size_t base = ((size_t)(b*20 + oh))*20*256 + t;
  #pragma unroll
  for (int ow = 0; ow < 20; ++ow){
    float v = fmaxf(acc[ow] + bv, 0.f);
    unsigned short h = f2bf(v);
    outh[base + ow*256] = h;
    outl[base + ow*256] = f2bf(v - bf2f(h));
  }
}

// ---------------- K2: conv2 as implicit GEMM, split-bf16 3-pass MFMA ----------------
// M=9216 (b,oh,ow) x N=256 (oc), K=20736 = 81*(kh,kw) * 256 ic. split-K=8 via atomics.
__global__ __launch_bounds__(256) void conv2_mfma(const unsigned short* __restrict__ in1h,
    const unsigned short* __restrict__ BTh, float* __restrict__ out){
  __shared__ __align__(16) unsigned short lds[16384]; // Ah|Al|Bh|Bl, 4096 shorts each
  const int t = threadIdx.x;
  const int lane = t & 63, w = t >> 6;
  const int m0 = blockIdx.y * 128, n0 = blockIdx.x * 128;
  const int rowA = t >> 2, seg = t & 3;

  const unsigned short* aS[2];
  const unsigned short* bS[2];
  #pragma unroll
  for (int h = 0; h < 2; ++h){
    int m = m0 + h*64 + rowA;
    int bb = m / 36, s = m - bb*36, oh = s / 6, ow = s - oh*6;
    aS[h] = in1h + ((size_t)((bb*20 + 2*oh)*20 + 2*ow))*256 + seg*8;
    int n = n0 + h*64 + rowA;
    bS[h] = BTh + (size_t)n*20736 + seg*8;
  }
  unsigned short* dstA = &lds[rowA*32 + seg*8];
  unsigned short* dstB = &lds[8192 + rowA*32 + seg*8];

  fvec4 acc[4][4];
  #pragma unroll
  for (int i=0;i<4;++i)
    #pragma unroll
    for (int j=0;j<4;++j) acc[i][j] = (fvec4){0.f,0.f,0.f,0.f};

  const int qm = (w >> 1)*64, qn = (w & 1)*64;
  const int ks0 = blockIdx.z * 81, ks1 = ks0 + 81;

  for (int ks = ks0; ks < ks1; ++ks){
    int kk = ks >> 3;
    int kh = kk / 9, kw = kk - kh*9;
    int aoff = (kh*20 + kw)*256 + (ks & 7)*32;
    int boff = ks*32;
    #pragma unroll
    for (int h = 0; h < 2; ++h){
      async16(dstA + h*2048,        aS[h] + aoff);
      async16(dstA + 4096 + h*2048, aS[h] + IN1_ELEMS + aoff);
      async16(dstB + h*2048,        bS[h] + boff);
      async16(dstB + 4096 + h*2048, bS[h] + BT_ELEMS + boff);
    }
    __syncthreads();
    short8 ah[4], al[4], bh[4], bl[4];
    #pragma unroll
    for (int i=0;i<4;++i){
      int ro = (qm + i*16 + (lane & 15))*32 + (lane >> 4)*8;
      ah[i] = *(const short8*)&lds[ro];
      al[i] = *(const short8*)&lds[4096 + ro];
    }
    #pragma unroll
    for (int j=0;j<4;++j){
      int ro = (qn + j*16 + (lane & 15))*32 + (lane >> 4)*8;
      bh[j] = *(const short8*)&lds[8192 + ro];
      bl[j] = *(const short8*)&lds[12288 + ro];
    }
    #pragma unroll
    for (int i=0;i<4;++i)
      #pragma unroll
      for (int j=0;j<4;++j){
        acc[i][j] = mfma_bf16(ah[i], bh[j], acc[i][j]);
        acc[i][j] = mfma_bf16(ah[i], bl[j], acc[i][j]);
        acc[i][j] = mfma_bf16(al[i], bh[j], acc[i][j]);
      }
    __syncthreads();
  }
  #pragma unroll
  for (int i=0;i<4;++i){
    int gm = m0 + qm + i*16 + ((lane >> 4) << 2);
    #pragma unroll
    for (int j=0;j<4;++j){
      int gn = n0 + qn + j*16 + (lane & 15);
      #pragma unroll
      for (int r=0;r<4;++r)
        atomicAdd(&out[(size_t)(gm + r)*256 + gn], acc[i][j][r]);
    }
  }
}

// ---------------- K3: bias + relu + squash -> pc ----------------
__global__ __launch_bounds__(256) void squash_pc_kernel(const float* __restrict__ c2out,
    const float* __restrict__ b2, float* __restrict__ pc){
  int g = blockIdx.x*256 + threadIdx.x;   // 294912 capsules
  const float* s = c2out + (size_t)g*8;
  int oc0 = (g & 31) * 8;
  float v[8], sq = 0.f;
  #pragma unroll
  for (int e=0;e<8;++e){ float x = fmaxf(s[e] + b2[oc0+e], 0.f); v[e] = x; sq += x*x; }
  float fac = sq / ((1.f + sq) * sqrtf(sq + EPS));
  float* o = pc + (size_t)g*8;
  #pragma unroll
  for (int e=0;e<8;++e) o[e] = v[e]*fac;
}

// ---------------- K4a: u_hat (fp32) + s1 partials ----------------
__global__ __launch_bounds__(256) void uhat_producer(const float* __restrict__ pc,
    const float* __restrict__ Wm, float* __restrict__ uhat, float* __restrict__ s1){
  __shared__ float pcl[8192]; // [64 b][16 n][8 i]
  int t = threadIdx.x;
  int n0 = blockIdx.x * 16, b0 = blockIdx.y * 64;
  #pragma unroll
  for (int p = 0; p < 32; ++p){
    int f = p*256 + t;
    int bl = f >> 7, rem = f & 127;
    pcl[f] = pc[((size_t)(b0 + bl)*1152 + n0)*8 + rem];
  }
  __syncthreads();
  for (int r = 0; r < 40; ++r){
    int item = r*256 + t;               // (b_local, cj)
    int bl = item / 160, cj = item - bl*160;
    float s1a = 0.f;
    size_t ub = ((size_t)(b0 + bl)*1152 + n0)*160 + cj;
    const float* pb = &pcl[bl*128];
    #pragma unroll 4
    for (int nl = 0; nl < 16; ++nl){
      const float4* wp = (const float4*)&Wm[((size_t)(n0 + nl)*160 + cj)*8];
      float4 w0 = wp[0], w1 = wp[1];
      const float4* pp = (const float4*)&pb[nl*8];
      float4 p0 = pp[0], p1 = pp[1];
      float uh = w0.x*p0.x + w0.y*p0.y + w0.z*p0.z + w0.w*p0.w
               + w1.x*p1.x + w1.y*p1.y + w1.z*p1.z + w1.w*p1.w;
      uhat[ub + (size_t)nl*160] = uh;
      s1a += uh;
    }
    atomicAdd(&s1[(b0 + bl)*160 + cj], s1a);
  }
}

// ---------------- K4b: v1 = squash(s1/10) ----------------
__global__ __launch_bounds__(64) void squash_v1_kernel(const float* __restrict__ s1,
    float* __restrict__ v1){
  int g = blockIdx.x*64 + threadIdx.x;
  if (g >= 2560) return;
  const float* s = s1 + g*16;
  float x[16], sq = 0.f;
  #pragma unroll
  for (int j=0;j<16;++j){ float v = s[j]*0.1f; x[j] = v; sq += v*v; }
  float fac = sq / ((1.f + sq) * sqrtf(sq + EPS));
  float* o = v1 + g*16;
  #pragma unroll
  for (int j=0;j<16;++j) o[j] = x[j]*fac;
}

// ---------------- K4c: uv -> softmax -> s2 partials ----------------
__global__ __launch_bounds__(256) void routing_kernel(const float* __restrict__ uhat,
    const float* __restrict__ v1, float* __restrict__ s2){
  __shared__ float uvl[1280];   // [128 n][10 c]
  __shared__ float v1l[160];
  int t = threadIdx.x;
  int n0 = blockIdx.x * 128, b = blockIdx.y;
  if (t < 160) v1l[t] = v1[b*160 + t];
  __syncthreads();
  #pragma unroll
  for (int p = 0; p < 5; ++p){
    int item = p*256 + t;
    int nl = item / 10, c = item - nl*10;
    const float4* up = (const float4*)&uhat[((size_t)b*1152 + n0 + nl)*160 + c*16];
    const float* vv = &v1l[c*16];
    float4 q0 = up[0], q1 = up[1], q2 = up[2], q3 = up[3];
    float uv = q0.x*vv[0] + q0.y*vv[1] + q0.z*vv[2] + q0.w*vv[3]
             + q1.x*vv[4] + q1.y*vv[5] + q1.z*vv[6] + q1.w*vv[7]
             + q2.x*vv[8] + q2.y*vv[9] + q2.z*vv[10]+ q2.w*vv[11]
             + q3.x*vv[12]+ q3.y*vv[13]+ q3.z*vv[14]+ q3.w*vv[15];
    uvl[item] = uv;
  }
  __syncthreads();
  if (t < 128){
    float* row = &uvl[t*10];
    float mx = row[0];
    #pragma unroll
    for (int c=1;c<10;++c) mx = fmaxf(mx, row[c]);
    float e[10], sum = 0.f;
    #pragma unroll
    for (int c=0;c<10;++c){ e[c] = expf(row[c]-mx); sum += e[c]; }
    float inv = 1.f/sum;
    #pragma unroll
    for (int c=0;c<10;++c) row[c] = e[c]*inv;
  }
  __syncthreads();
  if (t < 160){
    int c = t >> 4;
    float a = 0.f;
    const float* ub = &uhat[((size_t)b*1152 + n0)*160 + t];
    for (int nl = 0; nl < 128; ++nl)
      a = fmaf(uvl[nl*10 + c], ub[(size_t)nl*160], a);
    atomicAdd(&s2[b*160 + t], a);
  }
}

// ---------------- K4d: v2, norms, argmax, mask ----------------
__global__ __launch_bounds__(64) void finalize_kernel(const float* __restrict__ s2,
    const int* __restrict__ target, float* __restrict__ out_norm,
    float* __restrict__ out_pred, float* __restrict__ masked){
  __shared__ float v2l[160];
  __shared__ float nrm[10];
  int b = blockIdx.x, t = threadIdx.x;
  if (t < 10){
    const float* s = s2 + b*160 + t*16;
    float x[16], sq = 0.f;
    #pragma unroll
    for (int j=0;j<16;++j){ x[j] = s[j]; sq += x[j]*x[j]; }
    float fac = sq / ((1.f + sq) * sqrtf(sq + EPS));
    float n2 = 0.f;
    #pragma unroll
    for (int j=0;j<16;++j){ float v = x[j]*fac; v2l[t*16+j] = v; n2 += v*v; }
    float nr = sqrtf(n2 + EPS);
    nrm[t] = nr;
    out_norm[b*10 + t] = nr;
  }
  __syncthreads();
  if (t == 0){
    int am = 0; float bv = nrm[0];
    #pragma unroll
    for (int c=1;c<10;++c) if (nrm[c] > bv){ bv = nrm[c]; am = c; }
    out_pred[b] = (float)am;
  }
  int tg = target[b];
  #pragma unroll
  for (int p = 0; p < 3; ++p){
    int cj = p*64 + t;
    if (cj < 160) masked[b*160 + cj] = ((cj >> 4) == tg) ? v2l[cj] : 0.f;
  }
}

// ---------------- decoder GEMMs (M=256 fixed) ----------------
__global__ __launch_bounds__(256) void dec_gemm(const float* __restrict__ A,
    const float* __restrict__ B, const float* __restrict__ bias, float* __restrict__ C,
    int K, int N, int act){
  int t = threadIdx.x;
  int n = blockIdx.x*64 + (t & 63);
  int m = blockIdx.y*4 + (t >> 6);
  if (n >= N) return;
  float acc = 0.f;
  const float* a = A + (size_t)m*K;
  const float* bp = B + n;
  #pragma unroll 8
  for (int k = 0; k < K; ++k) acc = fmaf(a[k], bp[(size_t)k*N], acc);
  acc += bias[n];
  if (act == 0) acc = fmaxf(acc, 0.f);
  else acc = 1.f/(1.f + expf(-acc));
  C[(size_t)m*N + n] = acc;
}

extern "C" void kernel_launch(void* const* d_in, const int* in_sizes, int n_in,
                              void* d_out, int out_size, void* d_ws, size_t ws_size,
                              hipStream_t stream) {
  const float* image   = (const float*)d_in[0];
  const int*   target  = (const int*)d_in[1];
  const float* conv1_w = (const float*)d_in[2];
  const float* conv1_b = (const float*)d_in[3];
  const float* conv2_w = (const float*)d_in[4];
  const float* conv2_b = (const float*)d_in[5];
  const float* Wm      = (const float*)d_in[6];
  const float* d1_w    = (const float*)d_in[7];
  const float* d1_b    = (const float*)d_in[8];
  const float* d2_w    = (const float*)d_in[9];
  const float* d2_b    = (const float*)d_in[10];
  const float* d3_w    = (const float*)d_in[11];
  const float* d3_b    = (const float*)d_in[12];

  char* ws = (char*)d_ws;
  // region plan (u_hat overlays conv-phase buffers, which are dead by then):
  unsigned short* in1h = (unsigned short*)(ws);               // +52428800: in1l
  unsigned short* BTh  = (unsigned short*)(ws + 104857600);   // +10616832: BTl
  float* uhat   = (float*)(ws);                               // [0, 188743680)
  float* c2out  = (float*)(ws + 126091264);                   // 9437184 B
  float* pc     = (float*)(ws + 188743680);                   // 9437184 B
  float* s1     = (float*)(ws + 198180864);                   // 163840 B
  float* s2     = (float*)(ws + 198344704);                   // 163840 B
  float* v1     = (float*)(ws + 198508544);                   // 163840 B
  float* masked = (float*)(ws + 198672384);                   // 163840 B
  float* h1     = (float*)(ws + 198836224);                   // 524288 B
  float* h2     = (float*)(ws + 199360512);                   // 1048576 B

  float* out_norm = (float*)d_out;            // 2560
  float* out_pred = out_norm + 2560;          // 256
  float* dec      = out_norm + 2816;          // 200704

  wt_kernel<<<dim3(324,4),256,0,stream>>>(conv2_w, BTh, BTh + BT_ELEMS);
  conv1_kernel<<<dim3(20,256),256,0,stream>>>(image, conv1_w, conv1_b, in1h, in1h + IN1_ELEMS);
  hipMemsetAsync(c2out, 0, 9437184, stream);
  conv2_mfma<<<dim3(2,72,8),256,0,stream>>>(in1h, BTh, c2out);
  squash_pc_kernel<<<dim3(1152),256,0,stream>>>(c2out, conv2_b, pc);
  hipMemsetAsync(s1, 0, 327680, stream);  // zero s1 + s2 (contiguous)
  uhat_producer<<<dim3(72,4),256,0,stream>>>(pc, Wm, uhat, s1);
  squash_v1_kernel<<<dim3(40),64,0,stream>>>(s1, v1);
  routing_kernel<<<dim3(9,256),256,0,stream>>>(uhat, v1, s2);
  finalize_kernel<<<dim3(256),64,0,stream>>>(s2, target, out_norm, out_pred, masked);
  dec_gemm<<<dim3(8,64),256,0,stream>>>(masked, d1_w, d1_b, h1, 160, 512, 0);
  dec_gemm<<<dim3(16,64),256,0,stream>>>(h1, d2_w, d2_b, h2, 512, 1024, 0);
  dec_gemm<<<dim3(13,64),256,0,stream>>>(h2, d3_w, d3_b, dec, 1024, 784, 1);
}